// Round 1
// baseline (1205.064 us; speedup 1.0000x reference)
//
#include <hip/hip_runtime.h>
#include <hip/hip_bf16.h>
#include <math.h>

// Problem constants (fixed by reference)
#define BDIM 8
#define LDIM 512
#define NDIM 64
#define FDIM 128
#define HDIM 8
#define EDIM 16
#define CH 64                 // chunk of L processed per iteration
#define NCHUNK (LDIM / CH)    // 8
#define XPITCH 136            // bf16 row pitch for x tile (128 + 8 pad, keeps 16B align)
#define WPITCH 136
#define QKPITCH 17            // fp32 pitch pad to break bank conflicts
#define EPSV 1e-6f

typedef __attribute__((ext_vector_type(8))) short bf16x8;   // 8 bf16 (4 VGPRs)
typedef __attribute__((ext_vector_type(4))) float f32x4;

__device__ __forceinline__ float phi_elu1(float x) {
    // phi(x) = elu(x) + 1 = x+1 (x>0) else exp(x)
    return x > 0.f ? x + 1.f : __expf(x);
}

// One block (256 thr) per (sequence s, head h). s = blockIdx>>3, h = blockIdx&7
// so the 8 head-blocks of a sequence are dispatch-adjacent (spread over XCDs,
// query rows served from L3 after first touch).
__global__ __launch_bounds__(256, 3)
void cla_fused_kernel(const float* __restrict__ query,
                      const float* __restrict__ Wq, const float* __restrict__ bq,
                      const float* __restrict__ Wk, const float* __restrict__ bk,
                      const float* __restrict__ Wv, const float* __restrict__ bv,
                      float* __restrict__ out)
{
    __shared__ __align__(16) __hip_bfloat16 xs[CH][XPITCH];     // x chunk, bf16
    __shared__ __align__(16) __hip_bfloat16 Wt[48][WPITCH];     // W slices transposed: Wt[col][k]
    __shared__ float2 qkL[CH * QKPITCH];                        // (phi(q), phi(k)) per (row, e)
    __shared__ float  vsL[CH * QKPITCH];                        // v per (row, f)
    __shared__ __align__(16) float osL[CH * EDIM];              // output staging
    __shared__ float  bsL[48];

    const int tid = threadIdx.x;
    const int s = blockIdx.x >> 3;
    const int h = blockIdx.x & 7;
    const int b = s >> 6;    // s / NDIM
    const int n = s & 63;    // s % NDIM

    // ---- once per block: stage transposed bf16 W slices (48 cols x 128 k) + biases ----
    for (int idx = tid; idx < 48 * FDIM; idx += 256) {
        int e16 = idx & 15;
        int kk  = (idx >> 4) & 127;
        int m   = idx >> 11;                       // 0=q,1=k,2=v
        const float* Wm = (m == 0) ? Wq : (m == 1) ? Wk : Wv;
        Wt[m * 16 + e16][kk] = __float2bfloat16(Wm[kk * FDIM + h * EDIM + e16]);
    }
    if (tid < 48) {
        const float* bm = (tid < 16) ? bq : (tid < 32) ? bk : bv;
        bsL[tid] = bm[h * EDIM + (tid & 15)];
    }

    // MFMA lane decomposition (16x16x32 bf16, verified layouts):
    //  A: lane l -> A[m = l&15][k = (l>>4)*8 + j]
    //  B: lane l -> B[k = (l>>4)*8 + j][n = l&15]
    //  D: lane l, reg r -> D[row = (l>>4)*4 + r][col = l&15]
    const int lid  = tid & 63;
    const int w    = tid >> 6;          // wave id: M-tile (rows 16w..16w+15)
    const int mrow = lid & 15;
    const int koff = (lid >> 4) * 8;
    const int r0   = (lid >> 4) * 4;

    // scan decomposition: thread owns state S[e][f]
    const int e = tid & 15;
    const int f = tid >> 4;

    float S = 0.f;      // S[e][f], persists across chunks
    float Ksum = 0.f;   // inclusive cumsum of phi(k)[e], persists across chunks

    for (int c = 0; c < NCHUNK; ++c) {
        const int l0 = c * CH;

        // ---- stage x chunk -> bf16 LDS (coalesced float4 global reads) ----
        for (int v = tid; v < CH * 32; v += 256) {
            int row = v >> 5;
            int c4  = v & 31;
            const float4 xv = *(const float4*)(query
                + (((size_t)b * LDIM + l0 + row) * NDIM + n) * FDIM + c4 * 4);
            xs[row][c4 * 4 + 0] = __float2bfloat16(xv.x);
            xs[row][c4 * 4 + 1] = __float2bfloat16(xv.y);
            xs[row][c4 * 4 + 2] = __float2bfloat16(xv.z);
            xs[row][c4 * 4 + 3] = __float2bfloat16(xv.w);
        }
        __syncthreads();

        // ---- projection: q,k,v chunk = x_chunk @ W-slices via MFMA ----
        #pragma unroll
        for (int nt = 0; nt < 3; ++nt) {          // 0=q, 1=k, 2=v (16 cols each)
            f32x4 acc = {0.f, 0.f, 0.f, 0.f};
            #pragma unroll
            for (int kq = 0; kq < 4; ++kq) {      // K = 128 = 4 x 32
                const int k0 = kq * 32 + koff;
                bf16x8 a  = *(const bf16x8*)&xs[16 * w + mrow][k0];
                bf16x8 bb = *(const bf16x8*)&Wt[nt * 16 + mrow][k0];
                acc = __builtin_amdgcn_mfma_f32_16x16x32_bf16(a, bb, acc, 0, 0, 0);
            }
            const float bias = bsL[nt * 16 + mrow];
            #pragma unroll
            for (int r = 0; r < 4; ++r) {
                const int row = 16 * w + r0 + r;
                float val = acc[r] + bias;
                if (nt == 0)      qkL[row * QKPITCH + mrow].x = phi_elu1(val);
                else if (nt == 1) qkL[row * QKPITCH + mrow].y = phi_elu1(val);
                else              vsL[row * QKPITCH + mrow]   = val;
            }
        }
        __syncthreads();

        // ---- causal scan over the chunk ----
        // o[i][f]   = sum_e q[i][e] * S_i[e][f]         (S_i inclusive of step i)
        // d[i]      = sum_e q[i][e] * Ksum_i[e] + eps   (inclusive cumsum)
        // out       = o / d
        // e-reduction = 4 shfl_xor levels (e = lane&15, stays in-wave).
        #pragma unroll 4
        for (int i = 0; i < CH; ++i) {
            const float2 qk = qkL[i * QKPITCH + e];   // broadcast reads
            const float  vv = vsL[i * QKPITCH + f];
            S = fmaf(qk.y, vv, S);
            Ksum += qk.y;
            float p  = qk.x * S;
            float p2 = qk.x * Ksum;
            p += __shfl_xor(p, 1);  p2 += __shfl_xor(p2, 1);
            p += __shfl_xor(p, 2);  p2 += __shfl_xor(p2, 2);
            p += __shfl_xor(p, 4);  p2 += __shfl_xor(p2, 4);
            p += __shfl_xor(p, 8);  p2 += __shfl_xor(p2, 8);
            if (e == 0) osL[i * EDIM + f] = p / (p2 + EPSV);
        }
        __syncthreads();

        // ---- write output chunk (coalesced float4) ----
        {
            const int i  = tid >> 2;
            const int f4 = tid & 3;
            float4 ov = *(const float4*)&osL[i * EDIM + f4 * 4];
            *(float4*)(out + (((size_t)b * LDIM + l0 + i) * NDIM + n) * (HDIM * EDIM)
                       + h * EDIM + f4 * 4) = ov;
        }
        __syncthreads();
    }
}

extern "C" void kernel_launch(void* const* d_in, const int* in_sizes, int n_in,
                              void* d_out, int out_size, void* d_ws, size_t ws_size,
                              hipStream_t stream) {
    const float* query = (const float*)d_in[0];
    const float* Wq = (const float*)d_in[1];
    const float* bq = (const float*)d_in[2];
    const float* Wk = (const float*)d_in[3];
    const float* bk = (const float*)d_in[4];
    const float* Wv = (const float*)d_in[5];
    const float* bv = (const float*)d_in[6];
    float* out = (float*)d_out;

    dim3 grid(512 * 8);   // (B*N) sequences x H heads; h = blockIdx & 7
    dim3 block(256);
    hipLaunchKernelGGL(cla_fused_kernel, grid, block, 0, stream,
                       query, Wq, bq, Wk, bk, Wv, bv, out);
}

// Round 2
// 538.961 us; speedup vs baseline: 2.2359x; 2.2359x over previous
//
#include <hip/hip_runtime.h>
#include <hip/hip_bf16.h>
#include <math.h>

// Problem constants (fixed by reference)
#define BDIM 8
#define LDIM 512
#define NDIM 64
#define FDIM 128
#define HDIM 8
#define EDIM 16
#define CH 64                 // chunk of L per iteration
#define NCHUNK (LDIM / CH)    // 8
#define EPSV 1e-6f

typedef __attribute__((ext_vector_type(8))) short bf16x8;   // 8 bf16 (4 VGPRs)
typedef __attribute__((ext_vector_type(4))) float f32x4;

__device__ __forceinline__ float phi_elu1(float x) {
    // phi(x) = elu(x) + 1 = x+1 (x>0) else exp(x)
    return x > 0.f ? x + 1.f : __expf(x);
}
__device__ __forceinline__ float bf2f(short s) {
    union { unsigned u; float f; } un;
    un.u = ((unsigned)(unsigned short)s) << 16;
    return un.f;
}

// Chunked causal linear attention, one block (256 thr / 4 waves) per (seq, head).
// Per chunk: Scores = phiQ phiK^T (MFMA, masked) ; O = Scores@V (MFMA) + phiQ@S_prev (fp32 VALU);
// denom = rowsum(masked scores) + phiQ . Ksum_prev ; S += K^T V (MFMA -> fp32 LDS).
// Sequential dependency: 8 chunks (vs 512 scan steps in R1).
__global__ __launch_bounds__(256, 3)
void cla_chunked_kernel(const float* __restrict__ query,
                        const float* __restrict__ Wq, const float* __restrict__ bq,
                        const float* __restrict__ Wk, const float* __restrict__ bk,
                        const float* __restrict__ Wv, const float* __restrict__ bv,
                        float* __restrict__ out)
{
    // LDS. Pitches chosen so b128 row reads are <=2-way bank-aliased (free, m136).
    __shared__ __align__(16) __hip_bfloat16 Wt[48][136];          // W slices transposed: Wt[col][k]
    __shared__ __align__(16) unsigned char xsSc[CH * 136 * 2];    // union: xs[64][136] bf16  |  Sc[64][72] bf16
    __shared__ __align__(16) __hip_bfloat16 Qf[CH][40];           // phi(q); cols 16..31 kept zero (MFMA K=32 pad)
    __shared__ __align__(16) __hip_bfloat16 Kf[CH][40];           // phi(k); cols 16..31 kept zero
    __shared__ __align__(16) __hip_bfloat16 KfT[16][72];          // phi(k) transposed [e][row]
    __shared__ __align__(16) __hip_bfloat16 VfT[16][72];          // v transposed [f][row]
    __shared__ float Sst[16][17];                                  // running KV state, fp32
    __shared__ float KsumL[16];                                    // running cumsum of phi(k), fp32
    __shared__ float rsL[CH];                                      // per-row masked-score rowsums
    __shared__ float bsL[48];

    const int tid = threadIdx.x;
    const int s = blockIdx.x >> 3;
    const int h = blockIdx.x & 7;
    const int b = s >> 6;    // s / NDIM
    const int n = s & 63;    // s % NDIM

    __hip_bfloat16* xs = (__hip_bfloat16*)xsSc;     // pitch 136
    __hip_bfloat16* Sc = (__hip_bfloat16*)xsSc;     // pitch 72

    // ---- once per block: stage transposed bf16 W slices + biases; zero state ----
    for (int idx = tid; idx < 48 * FDIM; idx += 256) {
        int e16 = idx & 15;
        int kk  = (idx >> 4) & 127;
        int m   = idx >> 11;                       // 0=q,1=k,2=v
        const float* Wm = (m == 0) ? Wq : (m == 1) ? Wk : Wv;
        Wt[m * 16 + e16][kk] = __float2bfloat16(Wm[kk * FDIM + h * EDIM + e16]);
    }
    if (tid < 48) {
        const float* bm = (tid < 16) ? bq : (tid < 32) ? bk : bv;
        bsL[tid] = bm[h * EDIM + (tid & 15)];
    }
    for (int idx = tid; idx < CH * 16; idx += 256) {   // zero MFMA K-pad cols 16..31
        int rr = idx >> 4, cc = idx & 15;
        Qf[rr][16 + cc] = __float2bfloat16(0.f);
        Kf[rr][16 + cc] = __float2bfloat16(0.f);
    }
    for (int idx = tid; idx < 16 * 17; idx += 256) ((float*)Sst)[idx] = 0.f;
    if (tid < 16) KsumL[tid] = 0.f;

    // MFMA lane decomposition (16x16x32 bf16, m89-verified):
    //  A: lane l -> A[m = l&15][k = (l>>4)*8 + j]
    //  B: lane l -> B[k = (l>>4)*8 + j][n = l&15]
    //  D: lane l, reg r -> D[row = (l>>4)*4 + r][col = l&15]
    const int lid  = tid & 63;
    const int w    = tid >> 6;          // wave id = 16-row tile
    const int mrow = lid & 15;
    const int koff = (lid >> 4) * 8;
    const int r0   = (lid >> 4) * 4;

    __syncthreads();

    for (int c = 0; c < NCHUNK; ++c) {
        const int l0 = c * CH;

        // ---- phase 1: stage x chunk -> bf16 LDS (coalesced float4 reads) ----
        for (int v = tid; v < CH * 32; v += 256) {
            int row = v >> 5;
            int c4  = v & 31;
            const float4 xv = *(const float4*)(query
                + (((size_t)b * LDIM + l0 + row) * NDIM + n) * FDIM + c4 * 4);
            __hip_bfloat16* xr = xs + row * 136 + c4 * 4;
            xr[0] = __float2bfloat16(xv.x);
            xr[1] = __float2bfloat16(xv.y);
            xr[2] = __float2bfloat16(xv.z);
            xr[3] = __float2bfloat16(xv.w);
        }
        __syncthreads();

        // ---- phase 2: projection q,k,v = x @ W (MFMA), apply phi, store bf16 ----
        #pragma unroll
        for (int nt = 0; nt < 3; ++nt) {          // 0=q, 1=k, 2=v
            f32x4 acc = {0.f, 0.f, 0.f, 0.f};
            #pragma unroll
            for (int kq = 0; kq < 4; ++kq) {
                bf16x8 a  = *(const bf16x8*)(xs + (16 * w + mrow) * 136 + kq * 32 + koff);
                bf16x8 bb = *(const bf16x8*)&Wt[nt * 16 + mrow][kq * 32 + koff];
                acc = __builtin_amdgcn_mfma_f32_16x16x32_bf16(a, bb, acc, 0, 0, 0);
            }
            const float bias = bsL[nt * 16 + mrow];
            #pragma unroll
            for (int r = 0; r < 4; ++r) {
                const int row = 16 * w + r0 + r;
                float val = acc[r] + bias;
                if (nt == 0) {
                    Qf[row][mrow] = __float2bfloat16(phi_elu1(val));
                } else if (nt == 1) {
                    __hip_bfloat16 kb = __float2bfloat16(phi_elu1(val));
                    Kf[row][mrow] = kb;
                    KfT[mrow][row] = kb;
                } else {
                    VfT[mrow][row] = __float2bfloat16(val);
                }
            }
        }
        __syncthreads();

        // ---- phase 3: masked scores tile-row w (MFMA), rowsums, zero-pad tile ----
        {
            float rsacc[4] = {0.f, 0.f, 0.f, 0.f};
            for (int nt = 0; nt <= w; ++nt) {
                f32x4 sacc = {0.f, 0.f, 0.f, 0.f};
                bf16x8 a  = *(const bf16x8*)&Qf[16 * w + mrow][koff];
                bf16x8 bb = *(const bf16x8*)&Kf[16 * nt + mrow][koff];
                sacc = __builtin_amdgcn_mfma_f32_16x16x32_bf16(a, bb, sacc, 0, 0, 0);
                #pragma unroll
                for (int r = 0; r < 4; ++r) {
                    const int gi = 16 * w + r0 + r;   // query row
                    const int gj = 16 * nt + mrow;    // key row
                    float val = (gj <= gi) ? sacc[r] : 0.f;
                    Sc[gi * 72 + gj] = __float2bfloat16(val);
                    rsacc[r] += val;
                }
            }
            if (w == 0 || w == 2) {                   // zero the 16x16 tile right of diagonal
                const int rr = 16 * w + (lid >> 2);
                const int cc = 16 * (w + 1) + (lid & 3) * 4;
                *(uint2*)&Sc[rr * 72 + cc] = (uint2){0u, 0u};
            }
            #pragma unroll
            for (int r = 0; r < 4; ++r) {
                float p = rsacc[r];
                p += __shfl_xor(p, 1);
                p += __shfl_xor(p, 2);
                p += __shfl_xor(p, 4);
                p += __shfl_xor(p, 8);
                if (mrow == 0) rsL[16 * w + r0 + r] = p;
            }
        }
        __syncthreads();

        // ---- phase 4: O_intra (MFMA) + DeltaS (MFMA, wave0) + O_inter/denom (fp32) ----
        f32x4 oacc = {0.f, 0.f, 0.f, 0.f};
        const int nmf = (w <= 1) ? 1 : 2;
        for (int kc = 0; kc < nmf; ++kc) {
            bf16x8 a  = *(const bf16x8*)&Sc[(16 * w + mrow) * 72 + kc * 32 + koff];
            bf16x8 bb = *(const bf16x8*)&VfT[mrow][kc * 32 + koff];
            oacc = __builtin_amdgcn_mfma_f32_16x16x32_bf16(a, bb, oacc, 0, 0, 0);
        }
        f32x4 dsacc = {0.f, 0.f, 0.f, 0.f};
        if (w == 0) {
            #pragma unroll
            for (int kc = 0; kc < 2; ++kc) {
                bf16x8 a  = *(const bf16x8*)&KfT[mrow][kc * 32 + koff];
                bf16x8 bb = *(const bf16x8*)&VfT[mrow][kc * 32 + koff];
                dsacc = __builtin_amdgcn_mfma_f32_16x16x32_bf16(a, bb, dsacc, 0, 0, 0);
            }
        }
        {
            float Sv[16], Kv[16];
            #pragma unroll
            for (int e = 0; e < 16; ++e) {
                Sv[e] = Sst[e][mrow];     // fixed f=mrow per lane; broadcast across quads
                Kv[e] = KsumL[e];
            }
            #pragma unroll
            for (int r = 0; r < 4; ++r) {
                const int gi = 16 * w + r0 + r;
                bf16x8 qa = *(const bf16x8*)&Qf[gi][0];
                bf16x8 qb = *(const bf16x8*)&Qf[gi][8];
                float oi = 0.f, di = 0.f;
                #pragma unroll
                for (int j = 0; j < 8; ++j) {
                    float qv = bf2f(qa[j]);
                    oi = fmaf(qv, Sv[j], oi);
                    di = fmaf(qv, Kv[j], di);
                }
                #pragma unroll
                for (int j = 0; j < 8; ++j) {
                    float qv = bf2f(qb[j]);
                    oi = fmaf(qv, Sv[8 + j], oi);
                    di = fmaf(qv, Kv[8 + j], di);
                }
                const float o = oacc[r] + oi;
                const float d = rsL[gi] + di + EPSV;
                out[(((size_t)b * LDIM + l0 + gi) * NDIM + n) * (HDIM * EDIM) + h * EDIM + mrow] = o / d;
            }
        }
        __syncthreads();

        // ---- phase 5: state update (wave0: S += K^T V; wave1 lanes 0..15: Ksum) ----
        if (w == 0) {
            #pragma unroll
            for (int r = 0; r < 4; ++r) Sst[r0 + r][mrow] += dsacc[r];
        }
        if (w == 1 && lid < 16) {
            float ssum = 0.f;
            const bf16x8* kp = (const bf16x8*)&KfT[lid][0];
            #pragma unroll
            for (int j = 0; j < 8; ++j) {
                bf16x8 kv8 = kp[j];
                #pragma unroll
                for (int t = 0; t < 8; ++t) ssum += bf2f(kv8[t]);
            }
            KsumL[lid] += ssum;
        }
        __syncthreads();
    }
}

extern "C" void kernel_launch(void* const* d_in, const int* in_sizes, int n_in,
                              void* d_out, int out_size, void* d_ws, size_t ws_size,
                              hipStream_t stream) {
    const float* query = (const float*)d_in[0];
    const float* Wq = (const float*)d_in[1];
    const float* bq = (const float*)d_in[2];
    const float* Wk = (const float*)d_in[3];
    const float* bk = (const float*)d_in[4];
    const float* Wv = (const float*)d_in[5];
    const float* bv = (const float*)d_in[6];
    float* out = (float*)d_out;

    dim3 grid(512 * 8);   // (B*N) sequences x H heads; h = blockIdx & 7
    dim3 block(256);
    hipLaunchKernelGGL(cla_chunked_kernel, grid, block, 0, stream,
                       query, Wq, bq, Wk, bk, Wv, bv, out);
}

// Round 3
// 445.282 us; speedup vs baseline: 2.7063x; 1.2104x over previous
//
#include <hip/hip_runtime.h>
#include <hip/hip_bf16.h>
#include <math.h>

// Problem constants (fixed by reference)
#define BDIM 8
#define LDIM 512
#define NDIM 64
#define FDIM 128
#define HDIM 8
#define EDIM 16
#define CH 64
#define NCHUNK (LDIM / CH)
#define EPSV 1e-6f

typedef __attribute__((ext_vector_type(8))) short bf16x8;   // 8 bf16 (4 VGPRs)
typedef __attribute__((ext_vector_type(4))) float f32x4;

__device__ __forceinline__ float phi_elu1(float x) {
    return x > 0.f ? x + 1.f : __expf(x);   // elu(x)+1
}
__device__ __forceinline__ float bf2f(short s) {
    union { unsigned u; float f; } un;
    un.u = ((unsigned)(unsigned short)s) << 16;
    return un.f;
}
__device__ __forceinline__ short f2bf(float x) {
    __hip_bfloat16 h = __float2bfloat16(x);
    union { __hip_bfloat16 h; short s; } un;
    un.h = h;
    return un.s;
}

// ===================== K1: projection for ALL heads ========================
// grid 4096 = (seq s)*8 + chunk c. Stages x chunk once (vs 8x in R2),
// projects 64x384 via MFMA with W B-frags loaded from L2-resident global,
// applies phi to q/k, writes bf16 [s][h][l][e] to workspace.
__global__ __launch_bounds__(256, 3)
void cla_proj(const float* __restrict__ query,
              const float* __restrict__ Wq, const float* __restrict__ bq,
              const float* __restrict__ Wk, const float* __restrict__ bk,
              const float* __restrict__ Wv, const float* __restrict__ bv,
              short* __restrict__ wsQ, short* __restrict__ wsK, short* __restrict__ wsV)
{
    __shared__ __align__(16) __hip_bfloat16 xs[CH][136];
    const int tid = threadIdx.x;
    const int s = blockIdx.x >> 3;
    const int c = blockIdx.x & 7;
    const int b = s >> 6, n = s & 63;
    const int l0 = c * CH;
    const int lid = tid & 63, w = tid >> 6;
    const int mrow = lid & 15, koff = (lid >> 4) * 8, r0 = (lid >> 4) * 4;

    for (int v = tid; v < CH * 32; v += 256) {
        int row = v >> 5, c4 = v & 31;
        float4 xv = *(const float4*)(query + (((size_t)b * LDIM + l0 + row) * NDIM + n) * FDIM + c4 * 4);
        __hip_bfloat16* xr = &xs[row][c4 * 4];
        xr[0] = __float2bfloat16(xv.x); xr[1] = __float2bfloat16(xv.y);
        xr[2] = __float2bfloat16(xv.z); xr[3] = __float2bfloat16(xv.w);
    }
    __syncthreads();

    // A-frags for all 4 row-tiles (MFMA 16x16x32: A[m=lane&15][k=quad*8+j])
    bf16x8 Af[4][4];
    #pragma unroll
    for (int rt = 0; rt < 4; ++rt)
        #pragma unroll
        for (int kq = 0; kq < 4; ++kq)
            Af[rt][kq] = *(const bf16x8*)&xs[16 * rt + mrow][kq * 32 + koff];

    // wave w owns col-tiles {6w..6w+5} of 24 (q0..q7 | k0..k7 | v0..v7)
    #pragma unroll 1
    for (int ct = 0; ct < 6; ++ct) {
        const int tci = 6 * w + ct;
        const int m = tci >> 3, hh = tci & 7;
        const float* Wm = (m == 0) ? Wq : (m == 1) ? Wk : Wv;
        const float* bm = (m == 0) ? bq : (m == 1) ? bk : bv;
        // B-frag: lane holds W[k=kq*32+quad*8+j][hh*16 + lane&15]  (L2-hot scalar loads)
        bf16x8 Wf[4];
        #pragma unroll
        for (int kq = 0; kq < 4; ++kq)
            #pragma unroll
            for (int j = 0; j < 8; ++j)
                Wf[kq][j] = f2bf(Wm[(kq * 32 + koff + j) * FDIM + hh * 16 + mrow]);
        f32x4 acc[4];
        #pragma unroll
        for (int rt = 0; rt < 4; ++rt) acc[rt] = (f32x4){0.f, 0.f, 0.f, 0.f};
        #pragma unroll
        for (int kq = 0; kq < 4; ++kq)
            #pragma unroll
            for (int rt = 0; rt < 4; ++rt)
                acc[rt] = __builtin_amdgcn_mfma_f32_16x16x32_bf16(Af[rt][kq], Wf[kq], acc[rt], 0, 0, 0);
        const float bias = bm[hh * 16 + mrow];
        short* dst = ((m == 0) ? wsQ : (m == 1) ? wsK : wsV)
                     + ((size_t)(s * 8 + hh) * LDIM + l0) * 16;
        #pragma unroll
        for (int rt = 0; rt < 4; ++rt)
            #pragma unroll
            for (int r = 0; r < 4; ++r) {
                int gi = 16 * rt + r0 + r;
                float val = acc[rt][r] + bias;
                if (m < 2) val = phi_elu1(val);
                dst[gi * 16 + mrow] = f2bf(val);
            }
    }
}

// ===================== K2: per-chunk KV-state + exclusive scan =============
// grid 4096 = (s*8+h), one wave. DeltaS_c = phiK_c^T V_c (2 MFMA/chunk),
// in-register 8-step exclusive prefix -> S_prev, Ksum_prev (fp32) to ws.
__global__ __launch_bounds__(64, 4)
void cla_state(const short* __restrict__ wsK, const short* __restrict__ wsV,
               float* __restrict__ Spre, float* __restrict__ Kpre)
{
    const int tid = threadIdx.x;
    const int sh = blockIdx.x;
    const int mrow = tid & 15, koff = (tid >> 4) * 8, r0 = (tid >> 4) * 4;
    const short* pk = wsK + (size_t)sh * LDIM * 16;
    const short* pv = wsV + (size_t)sh * LDIM * 16;
    float Srun[4] = {0.f, 0.f, 0.f, 0.f};
    float Krun = 0.f;
    for (int c = 0; c < NCHUNK; ++c) {
        float* sp = Spre + ((size_t)sh * NCHUNK + c) * 256;
        #pragma unroll
        for (int r = 0; r < 4; ++r) sp[(r0 + r) * 16 + mrow] = Srun[r];
        if (tid < 16) Kpre[((size_t)sh * NCHUNK + c) * 16 + tid] = Krun;
        f32x4 ds = {0.f, 0.f, 0.f, 0.f};
        float kp = 0.f;
        #pragma unroll
        for (int kc = 0; kc < 2; ++kc) {
            bf16x8 ka, vb;
            #pragma unroll
            for (int j = 0; j < 8; ++j) {
                int idx = (c * CH + kc * 32 + koff + j) * 16 + mrow;
                ka[j] = pk[idx];
                vb[j] = pv[idx];
            }
            ds = __builtin_amdgcn_mfma_f32_16x16x32_bf16(ka, vb, ds, 0, 0, 0);
            #pragma unroll
            for (int j = 0; j < 8; ++j) kp += bf2f(ka[j]);
        }
        kp += __shfl_xor(kp, 16);   // reduce partial key-sums across quads
        kp += __shfl_xor(kp, 32);
        Krun += kp;
        #pragma unroll
        for (int r = 0; r < 4; ++r) Srun[r] += ds[r];
    }
}

// ===================== K3: fully-parallel per-chunk attention ==============
// grid 32768 = (s, h, c). No chunk loop, ONE barrier. Scores+mask+O_intra
// (MFMA) + O_inter/denom vs fp32 S_prev/Ksum_prev.
__global__ __launch_bounds__(256, 4)
void cla_attn(const short* __restrict__ wsQ, const short* __restrict__ wsK,
              const short* __restrict__ wsV, const float* __restrict__ SpreG,
              const float* __restrict__ KpreG, float* __restrict__ out)
{
    __shared__ __align__(16) __hip_bfloat16 Qf[CH][40];   // cols 16..31 zero (K=32 pad)
    __shared__ __align__(16) __hip_bfloat16 Kf[CH][40];
    __shared__ __align__(16) __hip_bfloat16 VfT[16][72];  // V transposed [f][key]
    __shared__ __align__(16) __hip_bfloat16 Sc[CH][72];   // masked scores
    __shared__ float Sp[16][17];
    __shared__ float ks[16];

    const int tid = threadIdx.x;
    const int bi = blockIdx.x;
    const int s = bi >> 6, h = (bi >> 3) & 7, c = bi & 7;
    const int b = s >> 6, n = s & 63;
    const int l0 = c * CH;
    const size_t base = ((size_t)(s * 8 + h) * LDIM + l0) * 16;

    // ---- staging (coalesced uint4 from ws) ----
    if (tid < 128) {
        int row = tid >> 1, half = tid & 1;
        *(uint4*)&Qf[row][half * 8] = *(const uint4*)(wsQ + base + row * 16 + half * 8);
        *(uint4*)&Qf[row][16 + half * 8] = (uint4){0u, 0u, 0u, 0u};
    } else {
        int t = tid - 128, row = t >> 1, half = t & 1;
        *(uint4*)&Kf[row][half * 8] = *(const uint4*)(wsK + base + row * 16 + half * 8);
        *(uint4*)&Kf[row][16 + half * 8] = (uint4){0u, 0u, 0u, 0u};
    }
    {
        int row = tid >> 2, part = tid & 3;
        uint2 vv = *(const uint2*)(wsV + base + row * 16 + part * 4);
        const short* vs = (const short*)&vv;
        #pragma unroll
        for (int jj = 0; jj < 4; ++jj)
            *(short*)&VfT[part * 4 + jj][row] = vs[jj];
    }
    Sp[tid >> 4][tid & 15] = SpreG[((size_t)(s * 8 + h) * NCHUNK + c) * 256 + tid];
    if (tid < 16) ks[tid] = KpreG[((size_t)(s * 8 + h) * NCHUNK + c) * 16 + tid];
    __syncthreads();

    const int lid = tid & 63, w = tid >> 6;
    const int mrow = lid & 15, koff = (lid >> 4) * 8, r0 = (lid >> 4) * 4;

    // ---- scores tile-row w (wave-private; within-wave LDS ordering only) ----
    float rs[4];
    {
        float rsacc[4] = {0.f, 0.f, 0.f, 0.f};
        bf16x8 qa = *(const bf16x8*)&Qf[16 * w + mrow][koff];
        for (int nt = 0; nt <= w; ++nt) {
            f32x4 sacc = {0.f, 0.f, 0.f, 0.f};
            bf16x8 kb = *(const bf16x8*)&Kf[16 * nt + mrow][koff];
            sacc = __builtin_amdgcn_mfma_f32_16x16x32_bf16(qa, kb, sacc, 0, 0, 0);
            #pragma unroll
            for (int r = 0; r < 4; ++r) {
                int gi = 16 * w + r0 + r, gj = 16 * nt + mrow;
                float val = (gj <= gi) ? sacc[r] : 0.f;
                *(short*)&Sc[gi][gj] = f2bf(val);
                rsacc[r] += val;
            }
        }
        if (w == 0 || w == 2) {     // zero 16x16 tile right of diagonal (read by O-MFMA)
            int rr = 16 * w + (lid >> 2), cc = 16 * (w + 1) + (lid & 3) * 4;
            *(uint2*)&Sc[rr][cc] = (uint2){0u, 0u};
        }
        #pragma unroll
        for (int r = 0; r < 4; ++r) {
            float p = rsacc[r];
            p += __shfl_xor(p, 1); p += __shfl_xor(p, 2);
            p += __shfl_xor(p, 4); p += __shfl_xor(p, 8);
            rs[r] = p;              // row-sum, valid in every lane of the quad
        }
    }

    // ---- O_intra (MFMA) + O_inter/denom (fp32) + store ----
    f32x4 oacc = {0.f, 0.f, 0.f, 0.f};
    const int nmf = (w <= 1) ? 1 : 2;
    for (int kc = 0; kc < nmf; ++kc) {
        bf16x8 a  = *(const bf16x8*)&Sc[16 * w + mrow][kc * 32 + koff];
        bf16x8 bb = *(const bf16x8*)&VfT[mrow][kc * 32 + koff];
        oacc = __builtin_amdgcn_mfma_f32_16x16x32_bf16(a, bb, oacc, 0, 0, 0);
    }
    float Sv[16], Kv[16];
    #pragma unroll
    for (int e = 0; e < 16; ++e) { Sv[e] = Sp[e][mrow]; Kv[e] = ks[e]; }
    #pragma unroll
    for (int r = 0; r < 4; ++r) {
        int gi = 16 * w + r0 + r;
        bf16x8 qa = *(const bf16x8*)&Qf[gi][0];
        bf16x8 qb = *(const bf16x8*)&Qf[gi][8];
        float oi = 0.f, di = 0.f;
        #pragma unroll
        for (int j = 0; j < 8; ++j) { float qv = bf2f(qa[j]); oi = fmaf(qv, Sv[j], oi); di = fmaf(qv, Kv[j], di); }
        #pragma unroll
        for (int j = 0; j < 8; ++j) { float qv = bf2f(qb[j]); oi = fmaf(qv, Sv[8 + j], oi); di = fmaf(qv, Kv[8 + j], di); }
        float o = oacc[r] + oi, d = rs[r] + di + EPSV;
        out[(((size_t)b * LDIM + l0 + gi) * NDIM + n) * (HDIM * EDIM) + h * 16 + mrow] = o / d;
    }
}

// ===================== Fallback: R2 fused kernel (ws too small) ============
__global__ __launch_bounds__(256, 3)
void cla_chunked_kernel(const float* __restrict__ query,
                        const float* __restrict__ Wq, const float* __restrict__ bq,
                        const float* __restrict__ Wk, const float* __restrict__ bk,
                        const float* __restrict__ Wv, const float* __restrict__ bv,
                        float* __restrict__ out)
{
    __shared__ __align__(16) __hip_bfloat16 Wt[48][136];
    __shared__ __align__(16) unsigned char xsSc[CH * 136 * 2];
    __shared__ __align__(16) __hip_bfloat16 Qf[CH][40];
    __shared__ __align__(16) __hip_bfloat16 Kf[CH][40];
    __shared__ __align__(16) __hip_bfloat16 KfT[16][72];
    __shared__ __align__(16) __hip_bfloat16 VfT[16][72];
    __shared__ float Sst[16][17];
    __shared__ float KsumL[16];
    __shared__ float rsL[CH];
    __shared__ float bsL[48];

    const int tid = threadIdx.x;
    const int s = blockIdx.x >> 3;
    const int h = blockIdx.x & 7;
    const int b = s >> 6;
    const int n = s & 63;

    __hip_bfloat16* xs = (__hip_bfloat16*)xsSc;
    __hip_bfloat16* Sc = (__hip_bfloat16*)xsSc;

    for (int idx = tid; idx < 48 * FDIM; idx += 256) {
        int e16 = idx & 15;
        int kk  = (idx >> 4) & 127;
        int m   = idx >> 11;
        const float* Wm = (m == 0) ? Wq : (m == 1) ? Wk : Wv;
        Wt[m * 16 + e16][kk] = __float2bfloat16(Wm[kk * FDIM + h * EDIM + e16]);
    }
    if (tid < 48) {
        const float* bm = (tid < 16) ? bq : (tid < 32) ? bk : bv;
        bsL[tid] = bm[h * EDIM + (tid & 15)];
    }
    for (int idx = tid; idx < CH * 16; idx += 256) {
        int rr = idx >> 4, cc = idx & 15;
        Qf[rr][16 + cc] = __float2bfloat16(0.f);
        Kf[rr][16 + cc] = __float2bfloat16(0.f);
    }
    for (int idx = tid; idx < 16 * 17; idx += 256) ((float*)Sst)[idx] = 0.f;
    if (tid < 16) KsumL[tid] = 0.f;

    const int lid  = tid & 63;
    const int w    = tid >> 6;
    const int mrow = lid & 15;
    const int koff = (lid >> 4) * 8;
    const int r0   = (lid >> 4) * 4;

    __syncthreads();

    for (int c = 0; c < NCHUNK; ++c) {
        const int l0 = c * CH;
        for (int v = tid; v < CH * 32; v += 256) {
            int row = v >> 5;
            int c4  = v & 31;
            const float4 xv = *(const float4*)(query
                + (((size_t)b * LDIM + l0 + row) * NDIM + n) * FDIM + c4 * 4);
            __hip_bfloat16* xr = xs + row * 136 + c4 * 4;
            xr[0] = __float2bfloat16(xv.x);
            xr[1] = __float2bfloat16(xv.y);
            xr[2] = __float2bfloat16(xv.z);
            xr[3] = __float2bfloat16(xv.w);
        }
        __syncthreads();

        #pragma unroll
        for (int nt = 0; nt < 3; ++nt) {
            f32x4 acc = {0.f, 0.f, 0.f, 0.f};
            #pragma unroll
            for (int kq = 0; kq < 4; ++kq) {
                bf16x8 a  = *(const bf16x8*)(xs + (16 * w + mrow) * 136 + kq * 32 + koff);
                bf16x8 bb = *(const bf16x8*)&Wt[nt * 16 + mrow][kq * 32 + koff];
                acc = __builtin_amdgcn_mfma_f32_16x16x32_bf16(a, bb, acc, 0, 0, 0);
            }
            const float bias = bsL[nt * 16 + mrow];
            #pragma unroll
            for (int r = 0; r < 4; ++r) {
                const int row = 16 * w + r0 + r;
                float val = acc[r] + bias;
                if (nt == 0) {
                    Qf[row][mrow] = __float2bfloat16(phi_elu1(val));
                } else if (nt == 1) {
                    __hip_bfloat16 kb = __float2bfloat16(phi_elu1(val));
                    Kf[row][mrow] = kb;
                    KfT[mrow][row] = kb;
                } else {
                    VfT[mrow][row] = __float2bfloat16(val);
                }
            }
        }
        __syncthreads();

        {
            float rsacc[4] = {0.f, 0.f, 0.f, 0.f};
            for (int nt = 0; nt <= w; ++nt) {
                f32x4 sacc = {0.f, 0.f, 0.f, 0.f};
                bf16x8 a  = *(const bf16x8*)&Qf[16 * w + mrow][koff];
                bf16x8 bb = *(const bf16x8*)&Kf[16 * nt + mrow][koff];
                sacc = __builtin_amdgcn_mfma_f32_16x16x32_bf16(a, bb, sacc, 0, 0, 0);
                #pragma unroll
                for (int r = 0; r < 4; ++r) {
                    const int gi = 16 * w + r0 + r;
                    const int gj = 16 * nt + mrow;
                    float val = (gj <= gi) ? sacc[r] : 0.f;
                    Sc[gi * 72 + gj] = __float2bfloat16(val);
                    rsacc[r] += val;
                }
            }
            if (w == 0 || w == 2) {
                const int rr = 16 * w + (lid >> 2);
                const int cc = 16 * (w + 1) + (lid & 3) * 4;
                *(uint2*)&Sc[rr * 72 + cc] = (uint2){0u, 0u};
            }
            #pragma unroll
            for (int r = 0; r < 4; ++r) {
                float p = rsacc[r];
                p += __shfl_xor(p, 1);
                p += __shfl_xor(p, 2);
                p += __shfl_xor(p, 4);
                p += __shfl_xor(p, 8);
                if (mrow == 0) rsL[16 * w + r0 + r] = p;
            }
        }
        __syncthreads();

        f32x4 oacc = {0.f, 0.f, 0.f, 0.f};
        const int nmf = (w <= 1) ? 1 : 2;
        for (int kc = 0; kc < nmf; ++kc) {
            bf16x8 a  = *(const bf16x8*)&Sc[(16 * w + mrow) * 72 + kc * 32 + koff];
            bf16x8 bb = *(const bf16x8*)&VfT[mrow][kc * 32 + koff];
            oacc = __builtin_amdgcn_mfma_f32_16x16x32_bf16(a, bb, oacc, 0, 0, 0);
        }
        f32x4 dsacc = {0.f, 0.f, 0.f, 0.f};
        if (w == 0) {
            #pragma unroll
            for (int kc = 0; kc < 2; ++kc) {
                bf16x8 a  = *(const bf16x8*)&KfT[mrow][kc * 32 + koff];
                bf16x8 bb = *(const bf16x8*)&VfT[mrow][kc * 32 + koff];
                dsacc = __builtin_amdgcn_mfma_f32_16x16x32_bf16(a, bb, dsacc, 0, 0, 0);
            }
        }
        {
            float Sv[16], Kv[16];
            #pragma unroll
            for (int e = 0; e < 16; ++e) {
                Sv[e] = Sst[e][mrow];
                Kv[e] = KsumL[e];
            }
            #pragma unroll
            for (int r = 0; r < 4; ++r) {
                const int gi = 16 * w + r0 + r;
                bf16x8 qa = *(const bf16x8*)&Qf[gi][0];
                bf16x8 qb = *(const bf16x8*)&Qf[gi][8];
                float oi = 0.f, di = 0.f;
                #pragma unroll
                for (int j = 0; j < 8; ++j) {
                    float qv = bf2f(qa[j]);
                    oi = fmaf(qv, Sv[j], oi);
                    di = fmaf(qv, Kv[j], di);
                }
                #pragma unroll
                for (int j = 0; j < 8; ++j) {
                    float qv = bf2f(qb[j]);
                    oi = fmaf(qv, Sv[8 + j], oi);
                    di = fmaf(qv, Kv[8 + j], di);
                }
                const float o = oacc[r] + oi;
                const float d = rsL[gi] + di + EPSV;
                out[(((size_t)b * LDIM + l0 + gi) * NDIM + n) * (HDIM * EDIM) + h * EDIM + mrow] = o / d;
            }
        }
        __syncthreads();

        if (w == 0) {
            #pragma unroll
            for (int r = 0; r < 4; ++r) Sst[r0 + r][mrow] += dsacc[r];
        }
        if (w == 1 && lid < 16) {
            float ssum = 0.f;
            const bf16x8* kp = (const bf16x8*)&KfT[lid][0];
            #pragma unroll
            for (int j = 0; j < 8; ++j) {
                bf16x8 kv8 = kp[j];
                #pragma unroll
                for (int t = 0; t < 8; ++t) ssum += bf2f(kv8[t]);
            }
            KsumL[lid] += ssum;
        }
        __syncthreads();
    }
}

extern "C" void kernel_launch(void* const* d_in, const int* in_sizes, int n_in,
                              void* d_out, int out_size, void* d_ws, size_t ws_size,
                              hipStream_t stream) {
    const float* query = (const float*)d_in[0];
    const float* Wq = (const float*)d_in[1];
    const float* bq = (const float*)d_in[2];
    const float* Wk = (const float*)d_in[3];
    const float* bk = (const float*)d_in[4];
    const float* Wv = (const float*)d_in[5];
    const float* bv = (const float*)d_in[6];
    float* out = (float*)d_out;

    const size_t QKV = (size_t)512 * 8 * 512 * 16;        // 33,554,432 elems (bf16 each)
    const size_t SPRE = (size_t)512 * 8 * 8 * 256;        // 8,388,608 fp32
    const size_t KPRE = (size_t)512 * 8 * 8 * 16;         // 524,288 fp32
    const size_t need = QKV * 3 * 2 + SPRE * 4 + KPRE * 4; // 236,978,176 B

    if (ws_size >= need) {
        short* wsQ = (short*)d_ws;
        short* wsK = wsQ + QKV;
        short* wsV = wsK + QKV;
        float* Spre = (float*)(wsV + QKV);
        float* Kpre = Spre + SPRE;
        hipLaunchKernelGGL(cla_proj, dim3(4096), dim3(256), 0, stream,
                           query, Wq, bq, Wk, bk, Wv, bv, wsQ, wsK, wsV);
        hipLaunchKernelGGL(cla_state, dim3(4096), dim3(64), 0, stream,
                           wsK, wsV, Spre, Kpre);
        hipLaunchKernelGGL(cla_attn, dim3(32768), dim3(256), 0, stream,
                           wsQ, wsK, wsV, Spre, Kpre, out);
    } else {
        hipLaunchKernelGGL(cla_chunked_kernel, dim3(4096), dim3(256), 0, stream,
                           query, Wq, bq, Wk, bk, Wv, bv, out);
    }
}